// Round 9
// baseline (207.453 us; speedup 1.0000x reference)
//
#include <hip/hip_runtime.h>
#include <hip/hip_bf16.h>

#define B_  2
#define S_  2048
#define D_  1024
#define H_  16
#define HD_ 64

typedef __attribute__((ext_vector_type(8))) short bf16x8;
typedef __attribute__((ext_vector_type(4))) float f32x4;

typedef __attribute__((address_space(1))) const short gbl_short;
typedef __attribute__((address_space(3))) short lds_short;

__device__ __forceinline__ short f2bf(float f) {
  union { float f; unsigned u; } v; v.f = f;
  unsigned r = (v.u + 0x7FFFu + ((v.u >> 16) & 1u)) >> 16;
  return (short)r;
}

__device__ __forceinline__ short bf16s(float f) {
  __hip_bfloat16 h = __float2bfloat16(f);
  return *reinterpret_cast<short*>(&h);
}

// ---------------- cast x fp32 -> bf16 ----------------
__global__ __launch_bounds__(256) void cast_x_kernel(const float* __restrict__ x,
                                                     short* __restrict__ xb) {
  int i = blockIdx.x * 256 + threadIdx.x;
  float4 v = ((const float4*)x)[i];
  short4 o;
  o.x = f2bf(v.x); o.y = f2bf(v.y); o.z = f2bf(v.z); o.w = f2bf(v.w);
  ((short4*)xb)[i] = o;
}

// ---------------- transpose + cast weights ----------------
__global__ __launch_bounds__(256) void transpose_cast_w(
    const float* __restrict__ w0, const float* __restrict__ w1,
    const float* __restrict__ w2, const float* __restrict__ w3,
    short* __restrict__ t0, short* __restrict__ t1,
    short* __restrict__ t2, short* __restrict__ t3) {
  const float* W = blockIdx.z == 0 ? w0 : blockIdx.z == 1 ? w1 : blockIdx.z == 2 ? w2 : w3;
  short* T       = blockIdx.z == 0 ? t0 : blockIdx.z == 1 ? t1 : blockIdx.z == 2 ? t2 : t3;
  __shared__ float tile[32][33];
  int tx = threadIdx.x, ty = threadIdx.y;
  int x0 = blockIdx.x * 32, y0 = blockIdx.y * 32;
#pragma unroll
  for (int i = 0; i < 4; ++i)
    tile[ty + i * 8][tx] = W[(y0 + ty + i * 8) * D_ + x0 + tx];
  __syncthreads();
#pragma unroll
  for (int i = 0; i < 4; ++i)
    T[(x0 + ty + i * 8) * D_ + y0 + tx] = f2bf(tile[tx][ty + i * 8]);
}

// ---------------- QKV GEMM: 128x128, BK=32 double-buffered (1 barrier/iter) ----------------
// Q pre-scaled by 1/sqrt(HD)*log2(e) so attention can exp2 raw MFMA output.
__global__ __launch_bounds__(256) void qkv_gemm(
    const short* __restrict__ xb,
    const short* __restrict__ Wqt, const short* __restrict__ Wkt, const short* __restrict__ Wvt,
    const float* __restrict__ bq, const float* __restrict__ bk, const float* __restrict__ bv,
    short* __restrict__ Qb, short* __restrict__ Kb, short* __restrict__ Vtb) {
  const int which = blockIdx.z;
  const short* Bt   = which == 0 ? Wqt : which == 1 ? Wkt : Wvt;
  const float* bias = which == 0 ? bq  : which == 1 ? bk  : bv;
  const float scl   = which == 0 ? 0.125f * 1.44269504089f : 1.0f;
  const int lane = threadIdx.x & 63, wave = threadIdx.x >> 6;
  const int l15 = lane & 15, quad = lane >> 4;
  const int wm = wave & 1, wn = wave >> 1;
  const int m0 = blockIdx.x * 128, n0 = blockIdx.y * 128;
  const int srow = lane >> 2;
  const int skp  = (lane & 3) * 8;

  __shared__ short lA[2][128 * 32];
  __shared__ short lB[2][128 * 32];

  f32x4 acc[4][4];
#pragma unroll
  for (int mi = 0; mi < 4; ++mi)
#pragma unroll
    for (int ni = 0; ni < 4; ++ni) { f32x4 z = {0.f, 0.f, 0.f, 0.f}; acc[mi][ni] = z; }

  auto stage = [&](int it, int buf) {
    int kk = it * 32;
#pragma unroll
    for (int j = 0; j < 2; ++j) {
      int c = wave * 2 + j;
      int row = c * 16 + srow;
      __builtin_amdgcn_global_load_lds(
          (gbl_short*)(xb + (m0 + row) * D_ + kk + skp),
          (lds_short*)(&lA[buf][0] + c * 512 + lane * 8), 16, 0, 0);
      __builtin_amdgcn_global_load_lds(
          (gbl_short*)(Bt + (n0 + row) * D_ + kk + skp),
          (lds_short*)(&lB[buf][0] + c * 512 + lane * 8), 16, 0, 0);
    }
  };

  stage(0, 0);
  __syncthreads();
  for (int it = 0; it < 32; ++it) {
    int cur = it & 1;
    if (it < 31) stage(it + 1, cur ^ 1);
    bf16x8 af[4], bf[4];
#pragma unroll
    for (int i = 0; i < 4; ++i) {
      af[i] = *(const bf16x8*)(&lA[cur][0] + (wm * 64 + i * 16 + l15) * 32 + quad * 8);
      bf[i] = *(const bf16x8*)(&lB[cur][0] + (wn * 64 + i * 16 + l15) * 32 + quad * 8);
    }
#pragma unroll
    for (int mi = 0; mi < 4; ++mi)
#pragma unroll
      for (int ni = 0; ni < 4; ++ni)
        acc[mi][ni] = __builtin_amdgcn_mfma_f32_16x16x32_bf16(af[mi], bf[ni], acc[mi][ni], 0, 0, 0);
    if (it < 31) __syncthreads();
  }

#pragma unroll
  for (int mi = 0; mi < 4; ++mi) {
    int m = m0 + wm * 64 + mi * 16 + quad * 4;
    int bb = m >> 11;
    int s0 = m & (S_ - 1);
#pragma unroll
    for (int ni = 0; ni < 4; ++ni) {
      int n = n0 + wn * 64 + ni * 16 + l15;
      int h = n >> 6, hd = n & 63;
      float bsv = bias[n];
      if (which < 2) {
        short* dst = which == 0 ? Qb : Kb;
#pragma unroll
        for (int r = 0; r < 4; ++r)
          dst[((bb * H_ + h) * S_ + (s0 + r)) * HD_ + hd] = f2bf((acc[mi][ni][r] + bsv) * scl);
      } else {
        short4 pk;
        pk.x = f2bf(acc[mi][ni][0] + bsv);
        pk.y = f2bf(acc[mi][ni][1] + bsv);
        pk.z = f2bf(acc[mi][ni][2] + bsv);
        pk.w = f2bf(acc[mi][ni][3] + bsv);
        *(short4*)(Vtb + ((bb * H_ + h) * HD_ + hd) * S_ + s0) = pk;
      }
    }
  }
}

// ---------------- output projection: 128x64 tile, BK=32 double-buffered ----------------
__global__ __launch_bounds__(256) void out_gemm(
    const short* __restrict__ Ob, const short* __restrict__ Wot,
    const float* __restrict__ bo, float* __restrict__ out) {
  const int lane = threadIdx.x & 63, wave = threadIdx.x >> 6;
  const int l15 = lane & 15, quad = lane >> 4;
  const int m0 = blockIdx.x * 128, n0 = blockIdx.y * 64;
  const int srow = lane >> 2;
  const int skp  = (lane & 3) * 8;

  __shared__ short lA[2][128 * 32];
  __shared__ short lB[2][64 * 32];

  f32x4 acc[2][4];
#pragma unroll
  for (int mi = 0; mi < 2; ++mi)
#pragma unroll
    for (int ni = 0; ni < 4; ++ni) { f32x4 z = {0.f, 0.f, 0.f, 0.f}; acc[mi][ni] = z; }

  auto stage = [&](int it, int buf) {
    int kk = it * 32;
#pragma unroll
    for (int j = 0; j < 2; ++j) {
      int c = wave * 2 + j;
      __builtin_amdgcn_global_load_lds(
          (gbl_short*)(Ob + (m0 + c * 16 + srow) * D_ + kk + skp),
          (lds_short*)(&lA[buf][0] + c * 512 + lane * 8), 16, 0, 0);
    }
    __builtin_amdgcn_global_load_lds(
        (gbl_short*)(Wot + (n0 + wave * 16 + srow) * D_ + kk + skp),
        (lds_short*)(&lB[buf][0] + wave * 512 + lane * 8), 16, 0, 0);
  };

  stage(0, 0);
  __syncthreads();
  for (int it = 0; it < 32; ++it) {
    int cur = it & 1;
    if (it < 31) stage(it + 1, cur ^ 1);
    bf16x8 af[2], bf[4];
#pragma unroll
    for (int i = 0; i < 2; ++i)
      af[i] = *(const bf16x8*)(&lA[cur][0] + (wave * 32 + i * 16 + l15) * 32 + quad * 8);
#pragma unroll
    for (int i = 0; i < 4; ++i)
      bf[i] = *(const bf16x8*)(&lB[cur][0] + (i * 16 + l15) * 32 + quad * 8);
#pragma unroll
    for (int mi = 0; mi < 2; ++mi)
#pragma unroll
      for (int ni = 0; ni < 4; ++ni)
        acc[mi][ni] = __builtin_amdgcn_mfma_f32_16x16x32_bf16(af[mi], bf[ni], acc[mi][ni], 0, 0, 0);
    if (it < 31) __syncthreads();
  }

#pragma unroll
  for (int mi = 0; mi < 2; ++mi) {
    int m = m0 + wave * 32 + mi * 16 + quad * 4;
#pragma unroll
    for (int ni = 0; ni < 4; ++ni) {
      int n = n0 + ni * 16 + l15;
      float bsv = bo[n];
#pragma unroll
      for (int r = 0; r < 4; ++r)
        out[(m + r) * D_ + n] = acc[mi][ni][r] + bsv;
    }
  }
}

// ---------------- Flash attention v6b ----------------
// 256 thr = 4 waves. grp=wave>>1 takes a 1024-key half; wq=wave&1 takes 32 q.
// 32-key K/V tiles, double-buffered (stage(kt+1) before compute(kt); one
// barrier/iter). Buffer strides in SHORTS: K/V region 8192 shorts, buf stride
// 4096, grp stride 2048 (round-8 NaN was compute using buf*8192 = byte-unit
// mixup, reading the wrong region). LDS 36 KB -> 4 blocks/CU; grid 1024.
__global__ __launch_bounds__(256, 4) void attn_kernel(
    const short* __restrict__ Qb, const short* __restrict__ Kb,
    const short* __restrict__ Vtb, short* __restrict__ Ob) {
  const int qt = blockIdx.x, h = blockIdx.y, b = blockIdx.z;
  const int base = (b * H_ + h) * S_ * HD_;
  const int tid = threadIdx.x;
  const int lane = tid & 63, wave = tid >> 6;      // 0..3
  const int grp = wave >> 1;                       // key-half
  const int wq  = wave & 1;                        // q-subtile
  const int l15 = lane & 15, quad = lane >> 4;

  __shared__ __align__(16) char smem[36864];
  short* lK  = (short*)smem;                       // [2 buf][2 grp][32*64] shorts
  short* lV  = (short*)(smem + 16384);             // [2 buf][2 grp][64*32] shorts
  short* lPw = (short*)(smem + 32768);             // [4 waves][16*32] shorts

  const int q0 = qt * 64 + wq * 32;

  bf16x8 qf[2][2];
#pragma unroll
  for (int mi = 0; mi < 2; ++mi)
#pragma unroll
    for (int ks = 0; ks < 2; ++ks)
      qf[mi][ks] = *(const bf16x8*)(Qb + base + (q0 + mi * 16 + l15) * HD_ + ks * 32 + quad * 8);

  f32x4 oacc[2][4];
  f32x4 lacc[2];
#pragma unroll
  for (int mi = 0; mi < 2; ++mi) {
    f32x4 z = {0.f, 0.f, 0.f, 0.f};
    lacc[mi] = z;
#pragma unroll
    for (int nb = 0; nb < 4; ++nb) oacc[mi][nb] = z;
  }

  bf16x8 onesf;
#pragma unroll
  for (int i = 0; i < 8; ++i) onesf[i] = (short)0x3F80;   // bf16 1.0

  // staging (per 2-wave group = 128 lanes; tig = tid & 127)
  const int tig = tid & 127;
  const int slotK = tig & 7,  rowK = tig >> 3;     // K: [32 keys][64 hd]
  const int slotV = tig & 3,  rowV = tig >> 2;     // V: [64 hd][32 keys]
  const short* kp = Kb + base + (grp * 1024 + rowK) * HD_ + ((slotK ^ (rowK & 7)) * 8);
  const short* vp = Vtb + base + rowV * S_ + grp * 1024 + ((slotV ^ (rowV & 3)) * 8);
  lds_short* ldk = (lds_short*)(lK + grp * 2048 + tig * 8);
  lds_short* ldv = (lds_short*)(lV + grp * 2048 + tig * 8);

  auto stage = [&](int kt, int buf) {
#pragma unroll
    for (int j = 0; j < 2; ++j) {
      __builtin_amdgcn_global_load_lds((gbl_short*)(kp + kt * 32 * HD_ + j * 16 * HD_),
                                       ldk + buf * 4096 + j * 1024, 16, 0, 0);
      __builtin_amdgcn_global_load_lds((gbl_short*)(vp + kt * 32 + j * 32 * S_),
                                       ldv + buf * 4096 + j * 1024, 16, 0, 0);
    }
  };

  short* pwv = lPw + wave * 512;                   // 16 rows x 32 shorts
  const int swzK = l15 & 7;
  const int swzV = l15 & 3;

  stage(0, 0);
  __syncthreads();

  for (int kt = 0; kt < 32; ++kt) {
    const int buf = kt & 1;
    if (kt < 31) stage(kt + 1, buf ^ 1);

    const short* lKc = lK + buf * 4096 + grp * 2048;   // shorts
    const short* lVc = lV + buf * 4096 + grp * 2048;   // shorts

    // S = Q K^T (32q x 32keys per wave)
    f32x4 sacc[2][2];
#pragma unroll
    for (int mi = 0; mi < 2; ++mi)
#pragma unroll
      for (int nb = 0; nb < 2; ++nb) { f32x4 z = {0.f, 0.f, 0.f, 0.f}; sacc[mi][nb] = z; }
#pragma unroll
    for (int nb = 0; nb < 2; ++nb)
#pragma unroll
      for (int ks = 0; ks < 2; ++ks) {
        bf16x8 kf = *(const bf16x8*)(lKc + (nb * 16 + l15) * 64 + (((ks * 4 + quad) ^ swzK) * 8));
        sacc[0][nb] = __builtin_amdgcn_mfma_f32_16x16x32_bf16(qf[0][ks], kf, sacc[0][nb], 0, 0, 0);
        sacc[1][nb] = __builtin_amdgcn_mfma_f32_16x16x32_bf16(qf[1][ks], kf, sacc[1][nb], 0, 0, 0);
      }

    // P = exp2(S) -> wave-private LDS (16x32, reused across mi; DS in-order)
    bf16x8 af[2];
#pragma unroll
    for (int mi = 0; mi < 2; ++mi) {
#pragma unroll
      for (int nb = 0; nb < 2; ++nb)
#pragma unroll
        for (int r = 0; r < 4; ++r)
          pwv[(quad * 4 + r) * 32 + nb * 16 + l15] =
              bf16s(__builtin_amdgcn_exp2f(sacc[mi][nb][r]));
      af[mi] = *(const bf16x8*)(pwv + l15 * 32 + quad * 8);
    }

    // O += P V ; l += P 1
#pragma unroll
    for (int nbh = 0; nbh < 4; ++nbh) {
      bf16x8 vf = *(const bf16x8*)(lVc + (nbh * 16 + l15) * 32 + ((quad ^ swzV) * 8));
      oacc[0][nbh] = __builtin_amdgcn_mfma_f32_16x16x32_bf16(af[0], vf, oacc[0][nbh], 0, 0, 0);
      oacc[1][nbh] = __builtin_amdgcn_mfma_f32_16x16x32_bf16(af[1], vf, oacc[1][nbh], 0, 0, 0);
    }
    lacc[0] = __builtin_amdgcn_mfma_f32_16x16x32_bf16(af[0], onesf, lacc[0], 0, 0, 0);
    lacc[1] = __builtin_amdgcn_mfma_f32_16x16x32_bf16(af[1], onesf, lacc[1], 0, 0, 0);
    __syncthreads();
  }

  // merge the two key-halves through LDS, normalize + write
  float* exch = (float*)smem;                      // 2 wq x 32q x 64d f32 = 16 KB
  float* lex  = (float*)(smem + 16384);            // 64 floats
  if (grp == 1) {
#pragma unroll
    for (int mi = 0; mi < 2; ++mi)
#pragma unroll
      for (int nbh = 0; nbh < 4; ++nbh)
#pragma unroll
        for (int r = 0; r < 4; ++r)
          exch[wq * 2048 + (mi * 16 + quad * 4 + r) * 64 + nbh * 16 + l15] = oacc[mi][nbh][r];
    if (l15 == 0) {
#pragma unroll
      for (int mi = 0; mi < 2; ++mi)
#pragma unroll
        for (int r = 0; r < 4; ++r)
          lex[wq * 32 + mi * 16 + quad * 4 + r] = lacc[mi][r];
    }
  }
  __syncthreads();
  if (grp == 0) {
#pragma unroll
    for (int mi = 0; mi < 2; ++mi)
#pragma unroll
      for (int r = 0; r < 4; ++r) {
        int row = mi * 16 + quad * 4 + r;
        float l2 = lex[wq * 32 + row];
        float inv = 1.0f / (lacc[mi][r] + l2);
        int sg = q0 + row;
#pragma unroll
        for (int nbh = 0; nbh < 4; ++nbh) {
          float o2 = exch[wq * 2048 + row * 64 + nbh * 16 + l15];
          Ob[(b * S_ + sg) * D_ + h * HD_ + nbh * 16 + l15] =
              bf16s((oacc[mi][nbh][r] + o2) * inv);
        }
      }
  }
}

// ---------------- launcher ----------------
extern "C" void kernel_launch(void* const* d_in, const int* in_sizes, int n_in,
                              void* d_out, int out_size, void* d_ws, size_t ws_size,
                              hipStream_t stream) {
  (void)in_sizes; (void)n_in; (void)out_size; (void)ws_size;
  const float* x  = (const float*)d_in[0];
  const float* Wq = (const float*)d_in[1];
  const float* bq = (const float*)d_in[2];
  const float* Wk = (const float*)d_in[3];
  const float* bk = (const float*)d_in[4];
  const float* Wv = (const float*)d_in[5];
  const float* bv = (const float*)d_in[6];
  const float* Wo = (const float*)d_in[7];
  const float* bo = (const float*)d_in[8];
  float* out = (float*)d_out;

  char* ws = (char*)d_ws;
  short* xb  = (short*)(ws);
  short* Wqt = (short*)(ws + 8388608);
  short* Wkt = Wqt + 1048576;
  short* Wvt = Wkt + 1048576;
  short* Wot = Wvt + 1048576;
  short* Qb  = Wot + 1048576;
  short* Kb  = Qb + 4194304;
  short* Vtb = Kb + 4194304;
  short* Ob  = Vtb + 4194304;

  cast_x_kernel<<<4096, 256, 0, stream>>>(x, xb);
  transpose_cast_w<<<dim3(32, 32, 4), dim3(32, 8), 0, stream>>>(
      Wq, Wk, Wv, Wo, Wqt, Wkt, Wvt, Wot);
  qkv_gemm<<<dim3(32, 8, 3), 256, 0, stream>>>(
      xb, Wqt, Wkt, Wvt, bq, bk, bv, Qb, Kb, Vtb);
  attn_kernel<<<dim3(32, 16, 2), 256, 0, stream>>>(Qb, Kb, Vtb, Ob);
  out_gemm<<<dim3(32, 16), 256, 0, stream>>>(Ob, Wot, bo, out);
}

// Round 10
// 204.785 us; speedup vs baseline: 1.0130x; 1.0130x over previous
//
#include <hip/hip_runtime.h>
#include <hip/hip_bf16.h>

#define B_  2
#define S_  2048
#define D_  1024
#define H_  16
#define HD_ 64

typedef __attribute__((ext_vector_type(8))) short bf16x8;
typedef __attribute__((ext_vector_type(4))) float f32x4;

typedef __attribute__((address_space(1))) const short gbl_short;
typedef __attribute__((address_space(3))) short lds_short;

__device__ __forceinline__ short f2bf(float f) {
  union { float f; unsigned u; } v; v.f = f;
  unsigned r = (v.u + 0x7FFFu + ((v.u >> 16) & 1u)) >> 16;
  return (short)r;
}

__device__ __forceinline__ short bf16s(float f) {
  __hip_bfloat16 h = __float2bfloat16(f);
  return *reinterpret_cast<short*>(&h);
}

// ---------------- cast x fp32 -> bf16 ----------------
__global__ __launch_bounds__(256) void cast_x_kernel(const float* __restrict__ x,
                                                     short* __restrict__ xb) {
  int i = blockIdx.x * 256 + threadIdx.x;
  float4 v = ((const float4*)x)[i];
  short4 o;
  o.x = f2bf(v.x); o.y = f2bf(v.y); o.z = f2bf(v.z); o.w = f2bf(v.w);
  ((short4*)xb)[i] = o;
}

// ---------------- transpose + cast weights ----------------
__global__ __launch_bounds__(256) void transpose_cast_w(
    const float* __restrict__ w0, const float* __restrict__ w1,
    const float* __restrict__ w2, const float* __restrict__ w3,
    short* __restrict__ t0, short* __restrict__ t1,
    short* __restrict__ t2, short* __restrict__ t3) {
  const float* W = blockIdx.z == 0 ? w0 : blockIdx.z == 1 ? w1 : blockIdx.z == 2 ? w2 : w3;
  short* T       = blockIdx.z == 0 ? t0 : blockIdx.z == 1 ? t1 : blockIdx.z == 2 ? t2 : t3;
  __shared__ float tile[32][33];
  int tx = threadIdx.x, ty = threadIdx.y;
  int x0 = blockIdx.x * 32, y0 = blockIdx.y * 32;
#pragma unroll
  for (int i = 0; i < 4; ++i)
    tile[ty + i * 8][tx] = W[(y0 + ty + i * 8) * D_ + x0 + tx];
  __syncthreads();
#pragma unroll
  for (int i = 0; i < 4; ++i)
    T[(x0 + ty + i * 8) * D_ + y0 + tx] = f2bf(tile[tx][ty + i * 8]);
}

// ---------------- QKV GEMM: 128x128, BK=32 double-buffered (1 barrier/iter) ----------------
// Q pre-scaled by 1/sqrt(HD)*log2(e) so attention can exp2 raw MFMA output.
__global__ __launch_bounds__(256) void qkv_gemm(
    const short* __restrict__ xb,
    const short* __restrict__ Wqt, const short* __restrict__ Wkt, const short* __restrict__ Wvt,
    const float* __restrict__ bq, const float* __restrict__ bk, const float* __restrict__ bv,
    short* __restrict__ Qb, short* __restrict__ Kb, short* __restrict__ Vtb) {
  const int which = blockIdx.z;
  const short* Bt   = which == 0 ? Wqt : which == 1 ? Wkt : Wvt;
  const float* bias = which == 0 ? bq  : which == 1 ? bk  : bv;
  const float scl   = which == 0 ? 0.125f * 1.44269504089f : 1.0f;
  const int lane = threadIdx.x & 63, wave = threadIdx.x >> 6;
  const int l15 = lane & 15, quad = lane >> 4;
  const int wm = wave & 1, wn = wave >> 1;
  const int m0 = blockIdx.x * 128, n0 = blockIdx.y * 128;
  const int srow = lane >> 2;
  const int skp  = (lane & 3) * 8;

  __shared__ short lA[2][128 * 32];
  __shared__ short lB[2][128 * 32];

  f32x4 acc[4][4];
#pragma unroll
  for (int mi = 0; mi < 4; ++mi)
#pragma unroll
    for (int ni = 0; ni < 4; ++ni) { f32x4 z = {0.f, 0.f, 0.f, 0.f}; acc[mi][ni] = z; }

  auto stage = [&](int it, int buf) {
    int kk = it * 32;
#pragma unroll
    for (int j = 0; j < 2; ++j) {
      int c = wave * 2 + j;
      int row = c * 16 + srow;
      __builtin_amdgcn_global_load_lds(
          (gbl_short*)(xb + (m0 + row) * D_ + kk + skp),
          (lds_short*)(&lA[buf][0] + c * 512 + lane * 8), 16, 0, 0);
      __builtin_amdgcn_global_load_lds(
          (gbl_short*)(Bt + (n0 + row) * D_ + kk + skp),
          (lds_short*)(&lB[buf][0] + c * 512 + lane * 8), 16, 0, 0);
    }
  };

  stage(0, 0);
  __syncthreads();
  for (int it = 0; it < 32; ++it) {
    int cur = it & 1;
    if (it < 31) stage(it + 1, cur ^ 1);
    bf16x8 af[4], bf[4];
#pragma unroll
    for (int i = 0; i < 4; ++i) {
      af[i] = *(const bf16x8*)(&lA[cur][0] + (wm * 64 + i * 16 + l15) * 32 + quad * 8);
      bf[i] = *(const bf16x8*)(&lB[cur][0] + (wn * 64 + i * 16 + l15) * 32 + quad * 8);
    }
#pragma unroll
    for (int mi = 0; mi < 4; ++mi)
#pragma unroll
      for (int ni = 0; ni < 4; ++ni)
        acc[mi][ni] = __builtin_amdgcn_mfma_f32_16x16x32_bf16(af[mi], bf[ni], acc[mi][ni], 0, 0, 0);
    if (it < 31) __syncthreads();
  }

#pragma unroll
  for (int mi = 0; mi < 4; ++mi) {
    int m = m0 + wm * 64 + mi * 16 + quad * 4;
    int bb = m >> 11;
    int s0 = m & (S_ - 1);
#pragma unroll
    for (int ni = 0; ni < 4; ++ni) {
      int n = n0 + wn * 64 + ni * 16 + l15;
      int h = n >> 6, hd = n & 63;
      float bsv = bias[n];
      if (which < 2) {
        short* dst = which == 0 ? Qb : Kb;
#pragma unroll
        for (int r = 0; r < 4; ++r)
          dst[((bb * H_ + h) * S_ + (s0 + r)) * HD_ + hd] = f2bf((acc[mi][ni][r] + bsv) * scl);
      } else {
        short4 pk;
        pk.x = f2bf(acc[mi][ni][0] + bsv);
        pk.y = f2bf(acc[mi][ni][1] + bsv);
        pk.z = f2bf(acc[mi][ni][2] + bsv);
        pk.w = f2bf(acc[mi][ni][3] + bsv);
        *(short4*)(Vtb + ((bb * H_ + h) * HD_ + hd) * S_ + s0) = pk;
      }
    }
  }
}

// ---------------- output projection: 128x64 tile, BK=32 double-buffered ----------------
__global__ __launch_bounds__(256) void out_gemm(
    const short* __restrict__ Ob, const short* __restrict__ Wot,
    const float* __restrict__ bo, float* __restrict__ out) {
  const int lane = threadIdx.x & 63, wave = threadIdx.x >> 6;
  const int l15 = lane & 15, quad = lane >> 4;
  const int m0 = blockIdx.x * 128, n0 = blockIdx.y * 64;
  const int srow = lane >> 2;
  const int skp  = (lane & 3) * 8;

  __shared__ short lA[2][128 * 32];
  __shared__ short lB[2][64 * 32];

  f32x4 acc[2][4];
#pragma unroll
  for (int mi = 0; mi < 2; ++mi)
#pragma unroll
    for (int ni = 0; ni < 4; ++ni) { f32x4 z = {0.f, 0.f, 0.f, 0.f}; acc[mi][ni] = z; }

  auto stage = [&](int it, int buf) {
    int kk = it * 32;
#pragma unroll
    for (int j = 0; j < 2; ++j) {
      int c = wave * 2 + j;
      __builtin_amdgcn_global_load_lds(
          (gbl_short*)(Ob + (m0 + c * 16 + srow) * D_ + kk + skp),
          (lds_short*)(&lA[buf][0] + c * 512 + lane * 8), 16, 0, 0);
    }
    __builtin_amdgcn_global_load_lds(
        (gbl_short*)(Wot + (n0 + wave * 16 + srow) * D_ + kk + skp),
        (lds_short*)(&lB[buf][0] + wave * 512 + lane * 8), 16, 0, 0);
  };

  stage(0, 0);
  __syncthreads();
  for (int it = 0; it < 32; ++it) {
    int cur = it & 1;
    if (it < 31) stage(it + 1, cur ^ 1);
    bf16x8 af[2], bf[4];
#pragma unroll
    for (int i = 0; i < 2; ++i)
      af[i] = *(const bf16x8*)(&lA[cur][0] + (wave * 32 + i * 16 + l15) * 32 + quad * 8);
#pragma unroll
    for (int i = 0; i < 4; ++i)
      bf[i] = *(const bf16x8*)(&lB[cur][0] + (i * 16 + l15) * 32 + quad * 8);
#pragma unroll
    for (int mi = 0; mi < 2; ++mi)
#pragma unroll
      for (int ni = 0; ni < 4; ++ni)
        acc[mi][ni] = __builtin_amdgcn_mfma_f32_16x16x32_bf16(af[mi], bf[ni], acc[mi][ni], 0, 0, 0);
    if (it < 31) __syncthreads();
  }

#pragma unroll
  for (int mi = 0; mi < 2; ++mi) {
    int m = m0 + wave * 32 + mi * 16 + quad * 4;
#pragma unroll
    for (int ni = 0; ni < 4; ++ni) {
      int n = n0 + ni * 16 + l15;
      float bsv = bo[n];
#pragma unroll
      for (int r = 0; r < 4; ++r)
        out[(m + r) * D_ + n] = acc[mi][ni][r] + bsv;
    }
  }
}

// ---------------- Flash attention v7: v6b + conflict-free LDS layouts ----------------
// Changes vs v6b (all layout-only; fixes the 7.6M SQ_LDS_BANK_CONFLICT):
//  * P: row stride 40 shorts (16B-aligned) + 16-short-half XOR by row>>3.
//    Write banks: quads land on {0,16,8,24}-based groups -> conflict-free;
//    read l15*20 mod 32 walks all bank quads -> conflict-free b128.
//  * V: source-group swizzle (row>>1)&3 (was row&3): with the 64B row stride
//    this makes each 8-lane phase cover 8 distinct 4-bank spans.
__global__ __launch_bounds__(256, 4) void attn_kernel(
    const short* __restrict__ Qb, const short* __restrict__ Kb,
    const short* __restrict__ Vtb, short* __restrict__ Ob) {
  const int qt = blockIdx.x, h = blockIdx.y, b = blockIdx.z;
  const int base = (b * H_ + h) * S_ * HD_;
  const int tid = threadIdx.x;
  const int lane = tid & 63, wave = tid >> 6;      // 0..3
  const int grp = wave >> 1;                       // key-half
  const int wq  = wave & 1;                        // q-subtile
  const int l15 = lane & 15, quad = lane >> 4;

  __shared__ __align__(16) char smem[37888];
  short* lK  = (short*)smem;                       // [2 buf][2 grp][32*64] shorts
  short* lV  = (short*)(smem + 16384);             // [2 buf][2 grp][64*32] shorts
  short* lPw = (short*)(smem + 32768);             // [4 waves][16 rows * 40] shorts

  const int q0 = qt * 64 + wq * 32;

  bf16x8 qf[2][2];
#pragma unroll
  for (int mi = 0; mi < 2; ++mi)
#pragma unroll
    for (int ks = 0; ks < 2; ++ks)
      qf[mi][ks] = *(const bf16x8*)(Qb + base + (q0 + mi * 16 + l15) * HD_ + ks * 32 + quad * 8);

  f32x4 oacc[2][4];
  f32x4 lacc[2];
#pragma unroll
  for (int mi = 0; mi < 2; ++mi) {
    f32x4 z = {0.f, 0.f, 0.f, 0.f};
    lacc[mi] = z;
#pragma unroll
    for (int nb = 0; nb < 4; ++nb) oacc[mi][nb] = z;
  }

  bf16x8 onesf;
#pragma unroll
  for (int i = 0; i < 8; ++i) onesf[i] = (short)0x3F80;   // bf16 1.0

  // staging (per 2-wave group = 128 lanes; tig = tid & 127)
  const int tig = tid & 127;
  const int slotK = tig & 7,  rowK = tig >> 3;     // K: [32 keys][64 hd]
  const int slotV = tig & 3,  rowV = tig >> 2;     // V: [64 hd][32 keys]
  const short* kp = Kb + base + (grp * 1024 + rowK) * HD_ + ((slotK ^ (rowK & 7)) * 8);
  const short* vp = Vtb + base + rowV * S_ + grp * 1024 + ((slotV ^ ((rowV >> 1) & 3)) * 8);
  lds_short* ldk = (lds_short*)(lK + grp * 2048 + tig * 8);
  lds_short* ldv = (lds_short*)(lV + grp * 2048 + tig * 8);

  auto stage = [&](int kt, int buf) {
#pragma unroll
    for (int j = 0; j < 2; ++j) {
      __builtin_amdgcn_global_load_lds((gbl_short*)(kp + kt * 32 * HD_ + j * 16 * HD_),
                                       ldk + buf * 4096 + j * 1024, 16, 0, 0);
      __builtin_amdgcn_global_load_lds((gbl_short*)(vp + kt * 32 + j * 32 * S_),
                                       ldv + buf * 4096 + j * 1024, 16, 0, 0);
    }
  };

  short* pwv = lPw + wave * 640;                   // 16 rows x 40 shorts
  const int swzK = l15 & 7;
  const int vswz = (l15 >> 1) & 3;                 // (row>>1)&3 with row=nbh*16+l15
  // P read offset (conflict-free): row l15, half (quad>>1)^(l15>>3), 8-short sub (quad&1)
  const int pread = l15 * 40 + (((quad >> 1) ^ ((l15 >> 3) & 1)) * 16) + (quad & 1) * 8;
  short* pwrite = pwv + (quad * 4) * 40;           // + r*40 + half*16 + l15

  stage(0, 0);
  __syncthreads();

  for (int kt = 0; kt < 32; ++kt) {
    const int buf = kt & 1;
    if (kt < 31) stage(kt + 1, buf ^ 1);

    const short* lKc = lK + buf * 4096 + grp * 2048;   // shorts
    const short* lVc = lV + buf * 4096 + grp * 2048;   // shorts

    // S = Q K^T (32q x 32keys per wave)
    f32x4 sacc[2][2];
#pragma unroll
    for (int mi = 0; mi < 2; ++mi)
#pragma unroll
      for (int nb = 0; nb < 2; ++nb) { f32x4 z = {0.f, 0.f, 0.f, 0.f}; sacc[mi][nb] = z; }
#pragma unroll
    for (int nb = 0; nb < 2; ++nb)
#pragma unroll
      for (int ks = 0; ks < 2; ++ks) {
        bf16x8 kf = *(const bf16x8*)(lKc + (nb * 16 + l15) * 64 + (((ks * 4 + quad) ^ swzK) * 8));
        sacc[0][nb] = __builtin_amdgcn_mfma_f32_16x16x32_bf16(qf[0][ks], kf, sacc[0][nb], 0, 0, 0);
        sacc[1][nb] = __builtin_amdgcn_mfma_f32_16x16x32_bf16(qf[1][ks], kf, sacc[1][nb], 0, 0, 0);
      }

    // P = exp2(S) -> wave-private LDS (conflict-free layout), read af per mi
    bf16x8 af[2];
#pragma unroll
    for (int mi = 0; mi < 2; ++mi) {
#pragma unroll
      for (int nb = 0; nb < 2; ++nb) {
        int half = (nb ^ (quad >> 1)) * 16;
#pragma unroll
        for (int r = 0; r < 4; ++r)
          pwrite[r * 40 + half + l15] =
              bf16s(__builtin_amdgcn_exp2f(sacc[mi][nb][r]));
      }
      af[mi] = *(const bf16x8*)(pwv + pread);
    }

    // O += P V ; l += P 1
#pragma unroll
    for (int nbh = 0; nbh < 4; ++nbh) {
      bf16x8 vf = *(const bf16x8*)(lVc + (nbh * 16 + l15) * 32 + ((quad ^ vswz) * 8));
      oacc[0][nbh] = __builtin_amdgcn_mfma_f32_16x16x32_bf16(af[0], vf, oacc[0][nbh], 0, 0, 0);
      oacc[1][nbh] = __builtin_amdgcn_mfma_f32_16x16x32_bf16(af[1], vf, oacc[1][nbh], 0, 0, 0);
    }
    lacc[0] = __builtin_amdgcn_mfma_f32_16x16x32_bf16(af[0], onesf, lacc[0], 0, 0, 0);
    lacc[1] = __builtin_amdgcn_mfma_f32_16x16x32_bf16(af[1], onesf, lacc[1], 0, 0, 0);
    __syncthreads();
  }

  // merge the two key-halves through LDS, normalize + write
  float* exch = (float*)smem;                      // 2 wq x 32q x 64d f32 = 16 KB
  float* lex  = (float*)(smem + 16384);            // 64 floats
  if (grp == 1) {
#pragma unroll
    for (int mi = 0; mi < 2; ++mi)
#pragma unroll
      for (int nbh = 0; nbh < 4; ++nbh)
#pragma unroll
        for (int r = 0; r < 4; ++r)
          exch[wq * 2048 + (mi * 16 + quad * 4 + r) * 64 + nbh * 16 + l15] = oacc[mi][nbh][r];
    if (l15 == 0) {
#pragma unroll
      for (int mi = 0; mi < 2; ++mi)
#pragma unroll
        for (int r = 0; r < 4; ++r)
          lex[wq * 32 + mi * 16 + quad * 4 + r] = lacc[mi][r];
    }
  }
  __syncthreads();
  if (grp == 0) {
#pragma unroll
    for (int mi = 0; mi < 2; ++mi)
#pragma unroll
      for (int r = 0; r < 4; ++r) {
        int row = mi * 16 + quad * 4 + r;
        float l2 = lex[wq * 32 + row];
        float inv = 1.0f / (lacc[mi][r] + l2);
        int sg = q0 + row;
#pragma unroll
        for (int nbh = 0; nbh < 4; ++nbh) {
          float o2 = exch[wq * 2048 + row * 64 + nbh * 16 + l15];
          Ob[(b * S_ + sg) * D_ + h * HD_ + nbh * 16 + l15] =
              bf16s((oacc[mi][nbh][r] + o2) * inv);
        }
      }
  }
}

// ---------------- launcher ----------------
extern "C" void kernel_launch(void* const* d_in, const int* in_sizes, int n_in,
                              void* d_out, int out_size, void* d_ws, size_t ws_size,
                              hipStream_t stream) {
  (void)in_sizes; (void)n_in; (void)out_size; (void)ws_size;
  const float* x  = (const float*)d_in[0];
  const float* Wq = (const float*)d_in[1];
  const float* bq = (const float*)d_in[2];
  const float* Wk = (const float*)d_in[3];
  const float* bk = (const float*)d_in[4];
  const float* Wv = (const float*)d_in[5];
  const float* bv = (const float*)d_in[6];
  const float* Wo = (const float*)d_in[7];
  const float* bo = (const float*)d_in[8];
  float* out = (float*)d_out;

  char* ws = (char*)d_ws;
  short* xb  = (short*)(ws);
  short* Wqt = (short*)(ws + 8388608);
  short* Wkt = Wqt + 1048576;
  short* Wvt = Wkt + 1048576;
  short* Wot = Wvt + 1048576;
  short* Qb  = Wot + 1048576;
  short* Kb  = Qb + 4194304;
  short* Vtb = Kb + 4194304;
  short* Ob  = Vtb + 4194304;

  cast_x_kernel<<<4096, 256, 0, stream>>>(x, xb);
  transpose_cast_w<<<dim3(32, 32, 4), dim3(32, 8), 0, stream>>>(
      Wq, Wk, Wv, Wo, Wqt, Wkt, Wvt, Wot);
  qkv_gemm<<<dim3(32, 8, 3), 256, 0, stream>>>(
      xb, Wqt, Wkt, Wvt, bq, bk, bv, Qb, Kb, Vtb);
  attn_kernel<<<dim3(32, 16, 2), 256, 0, stream>>>(Qb, Kb, Vtb, Ob);
  out_gemm<<<dim3(32, 16), 256, 0, stream>>>(Ob, Wot, bo, out);
}

// Round 11
// 190.845 us; speedup vs baseline: 1.0870x; 1.0730x over previous
//
#include <hip/hip_runtime.h>
#include <hip/hip_bf16.h>

#define B_  2
#define S_  2048
#define D_  1024
#define H_  16
#define HD_ 64

typedef __attribute__((ext_vector_type(8))) short bf16x8;
typedef __attribute__((ext_vector_type(4))) short bf16x4;
typedef __attribute__((ext_vector_type(4))) float f32x4;

typedef __attribute__((address_space(1))) const short gbl_short;
typedef __attribute__((address_space(3))) short lds_short;

__device__ __forceinline__ short f2bf(float f) {
  union { float f; unsigned u; } v; v.f = f;
  unsigned r = (v.u + 0x7FFFu + ((v.u >> 16) & 1u)) >> 16;
  return (short)r;
}

__device__ __forceinline__ short bf16s(float f) {
  __hip_bfloat16 h = __float2bfloat16(f);
  return *reinterpret_cast<short*>(&h);
}

// ---------------- cast x fp32 -> bf16 ----------------
__global__ __launch_bounds__(256) void cast_x_kernel(const float* __restrict__ x,
                                                     short* __restrict__ xb) {
  int i = blockIdx.x * 256 + threadIdx.x;
  float4 v = ((const float4*)x)[i];
  short4 o;
  o.x = f2bf(v.x); o.y = f2bf(v.y); o.z = f2bf(v.z); o.w = f2bf(v.w);
  ((short4*)xb)[i] = o;
}

// ---------------- transpose + cast weights ----------------
__global__ __launch_bounds__(256) void transpose_cast_w(
    const float* __restrict__ w0, const float* __restrict__ w1,
    const float* __restrict__ w2, const float* __restrict__ w3,
    short* __restrict__ t0, short* __restrict__ t1,
    short* __restrict__ t2, short* __restrict__ t3) {
  const float* W = blockIdx.z == 0 ? w0 : blockIdx.z == 1 ? w1 : blockIdx.z == 2 ? w2 : w3;
  short* T       = blockIdx.z == 0 ? t0 : blockIdx.z == 1 ? t1 : blockIdx.z == 2 ? t2 : t3;
  __shared__ float tile[32][33];
  int tx = threadIdx.x, ty = threadIdx.y;
  int x0 = blockIdx.x * 32, y0 = blockIdx.y * 32;
#pragma unroll
  for (int i = 0; i < 4; ++i)
    tile[ty + i * 8][tx] = W[(y0 + ty + i * 8) * D_ + x0 + tx];
  __syncthreads();
#pragma unroll
  for (int i = 0; i < 4; ++i)
    T[(x0 + ty + i * 8) * D_ + y0 + tx] = f2bf(tile[tx][ty + i * 8]);
}

// ---------------- QKV GEMM: 128x128, BK=32 double-buffered (1 barrier/iter) ----------------
// Q pre-scaled by 1/sqrt(HD)*log2(e) so attention can exp2 raw MFMA output.
__global__ __launch_bounds__(256) void qkv_gemm(
    const short* __restrict__ xb,
    const short* __restrict__ Wqt, const short* __restrict__ Wkt, const short* __restrict__ Wvt,
    const float* __restrict__ bq, const float* __restrict__ bk, const float* __restrict__ bv,
    short* __restrict__ Qb, short* __restrict__ Kb, short* __restrict__ Vtb) {
  const int which = blockIdx.z;
  const short* Bt   = which == 0 ? Wqt : which == 1 ? Wkt : Wvt;
  const float* bias = which == 0 ? bq  : which == 1 ? bk  : bv;
  const float scl   = which == 0 ? 0.125f * 1.44269504089f : 1.0f;
  const int lane = threadIdx.x & 63, wave = threadIdx.x >> 6;
  const int l15 = lane & 15, quad = lane >> 4;
  const int wm = wave & 1, wn = wave >> 1;
  const int m0 = blockIdx.x * 128, n0 = blockIdx.y * 128;
  const int srow = lane >> 2;
  const int skp  = (lane & 3) * 8;

  __shared__ short lA[2][128 * 32];
  __shared__ short lB[2][128 * 32];

  f32x4 acc[4][4];
#pragma unroll
  for (int mi = 0; mi < 4; ++mi)
#pragma unroll
    for (int ni = 0; ni < 4; ++ni) { f32x4 z = {0.f, 0.f, 0.f, 0.f}; acc[mi][ni] = z; }

  auto stage = [&](int it, int buf) {
    int kk = it * 32;
#pragma unroll
    for (int j = 0; j < 2; ++j) {
      int c = wave * 2 + j;
      int row = c * 16 + srow;
      __builtin_amdgcn_global_load_lds(
          (gbl_short*)(xb + (m0 + row) * D_ + kk + skp),
          (lds_short*)(&lA[buf][0] + c * 512 + lane * 8), 16, 0, 0);
      __builtin_amdgcn_global_load_lds(
          (gbl_short*)(Bt + (n0 + row) * D_ + kk + skp),
          (lds_short*)(&lB[buf][0] + c * 512 + lane * 8), 16, 0, 0);
    }
  };

  stage(0, 0);
  __syncthreads();
  for (int it = 0; it < 32; ++it) {
    int cur = it & 1;
    if (it < 31) stage(it + 1, cur ^ 1);
    bf16x8 af[4], bf[4];
#pragma unroll
    for (int i = 0; i < 4; ++i) {
      af[i] = *(const bf16x8*)(&lA[cur][0] + (wm * 64 + i * 16 + l15) * 32 + quad * 8);
      bf[i] = *(const bf16x8*)(&lB[cur][0] + (wn * 64 + i * 16 + l15) * 32 + quad * 8);
    }
#pragma unroll
    for (int mi = 0; mi < 4; ++mi)
#pragma unroll
      for (int ni = 0; ni < 4; ++ni)
        acc[mi][ni] = __builtin_amdgcn_mfma_f32_16x16x32_bf16(af[mi], bf[ni], acc[mi][ni], 0, 0, 0);
    if (it < 31) __syncthreads();
  }

#pragma unroll
  for (int mi = 0; mi < 4; ++mi) {
    int m = m0 + wm * 64 + mi * 16 + quad * 4;
    int bb = m >> 11;
    int s0 = m & (S_ - 1);
#pragma unroll
    for (int ni = 0; ni < 4; ++ni) {
      int n = n0 + wn * 64 + ni * 16 + l15;
      int h = n >> 6, hd = n & 63;
      float bsv = bias[n];
      if (which < 2) {
        short* dst = which == 0 ? Qb : Kb;
#pragma unroll
        for (int r = 0; r < 4; ++r)
          dst[((bb * H_ + h) * S_ + (s0 + r)) * HD_ + hd] = f2bf((acc[mi][ni][r] + bsv) * scl);
      } else {
        short4 pk;
        pk.x = f2bf(acc[mi][ni][0] + bsv);
        pk.y = f2bf(acc[mi][ni][1] + bsv);
        pk.z = f2bf(acc[mi][ni][2] + bsv);
        pk.w = f2bf(acc[mi][ni][3] + bsv);
        *(short4*)(Vtb + ((bb * H_ + h) * HD_ + hd) * S_ + s0) = pk;
      }
    }
  }
}

// ---------------- output projection: 128x64 tile, BK=32 double-buffered ----------------
__global__ __launch_bounds__(256) void out_gemm(
    const short* __restrict__ Ob, const short* __restrict__ Wot,
    const float* __restrict__ bo, float* __restrict__ out) {
  const int lane = threadIdx.x & 63, wave = threadIdx.x >> 6;
  const int l15 = lane & 15, quad = lane >> 4;
  const int m0 = blockIdx.x * 128, n0 = blockIdx.y * 64;
  const int srow = lane >> 2;
  const int skp  = (lane & 3) * 8;

  __shared__ short lA[2][128 * 32];
  __shared__ short lB[2][64 * 32];

  f32x4 acc[2][4];
#pragma unroll
  for (int mi = 0; mi < 2; ++mi)
#pragma unroll
    for (int ni = 0; ni < 4; ++ni) { f32x4 z = {0.f, 0.f, 0.f, 0.f}; acc[mi][ni] = z; }

  auto stage = [&](int it, int buf) {
    int kk = it * 32;
#pragma unroll
    for (int j = 0; j < 2; ++j) {
      int c = wave * 2 + j;
      __builtin_amdgcn_global_load_lds(
          (gbl_short*)(Ob + (m0 + c * 16 + srow) * D_ + kk + skp),
          (lds_short*)(&lA[buf][0] + c * 512 + lane * 8), 16, 0, 0);
    }
    __builtin_amdgcn_global_load_lds(
        (gbl_short*)(Wot + (n0 + wave * 16 + srow) * D_ + kk + skp),
        (lds_short*)(&lB[buf][0] + wave * 512 + lane * 8), 16, 0, 0);
  };

  stage(0, 0);
  __syncthreads();
  for (int it = 0; it < 32; ++it) {
    int cur = it & 1;
    if (it < 31) stage(it + 1, cur ^ 1);
    bf16x8 af[2], bf[4];
#pragma unroll
    for (int i = 0; i < 2; ++i)
      af[i] = *(const bf16x8*)(&lA[cur][0] + (wave * 32 + i * 16 + l15) * 32 + quad * 8);
#pragma unroll
    for (int i = 0; i < 4; ++i)
      bf[i] = *(const bf16x8*)(&lB[cur][0] + (i * 16 + l15) * 32 + quad * 8);
#pragma unroll
    for (int mi = 0; mi < 2; ++mi)
#pragma unroll
      for (int ni = 0; ni < 4; ++ni)
        acc[mi][ni] = __builtin_amdgcn_mfma_f32_16x16x32_bf16(af[mi], bf[ni], acc[mi][ni], 0, 0, 0);
    if (it < 31) __syncthreads();
  }

#pragma unroll
  for (int mi = 0; mi < 2; ++mi) {
    int m = m0 + wave * 32 + mi * 16 + quad * 4;
#pragma unroll
    for (int ni = 0; ni < 4; ++ni) {
      int n = n0 + ni * 16 + l15;
      float bsv = bo[n];
#pragma unroll
      for (int r = 0; r < 4; ++r)
        out[(m + r) * D_ + n] = acc[mi][ni][r] + bsv;
    }
  }
}

// ---------------- Flash attention v8: register-only P (S^T trick) ----------------
// Compute S^T = mfma(A=K-frag, B=Q-frag): lane(l15,quad) gets S^T cols q=l15,
// rows key=nb*16+quad*4+r. With key ordering sigma(quad*8+j) =
// (j>>2)*16+quad*4+(j&3), the PV A-fragment is exp2(sacc[j>>2][j&3]) -- built
// entirely from the lane's own registers. P never touches LDS. V is consumed
// with the same sigma: two b64 reads per nbh (keys quad*4+0..3, 16+quad*4+0..3),
// conflict-free via (row>>2)&3 16B-group source swizzle.
// 256 thr = 4 waves = 2 wq (64q each) x 2 grp (1024-key halves). 32-key dbuf
// tiles, one barrier/iter. Epilogue merges the two key-halves via LDS.
// launch_bounds(256,2): VGPR cap 256 (~165 needed; min-waves=4 would spill).
__global__ __launch_bounds__(256, 2) void attn_kernel(
    const short* __restrict__ Qb, const short* __restrict__ Kb,
    const short* __restrict__ Vtb, short* __restrict__ Ob) {
  const int qt = blockIdx.x, h = blockIdx.y, b = blockIdx.z;
  const int base = (b * H_ + h) * S_ * HD_;
  const int tid = threadIdx.x;
  const int lane = tid & 63, wave = tid >> 6;      // 0..3
  const int grp = wave >> 1;                       // key-half
  const int wq  = wave & 1;                        // q-subtile (64 q)
  const int l15 = lane & 15, quad = lane >> 4;

  __shared__ __align__(16) char smem[33280];
  short* lK = (short*)smem;                        // [2 buf][2 grp][32key*64hd]
  short* lV = (short*)(smem + 16384);              // [2 buf][2 grp][64hd*32key]

  const int q0 = qt * 128 + wq * 64;

  bf16x8 qf[4][2];
#pragma unroll
  for (int mi = 0; mi < 4; ++mi)
#pragma unroll
    for (int ks = 0; ks < 2; ++ks)
      qf[mi][ks] = *(const bf16x8*)(Qb + base + (q0 + mi * 16 + l15) * HD_ + ks * 32 + quad * 8);

  f32x4 oacc[4][4];
  f32x4 lacc[4];
#pragma unroll
  for (int mi = 0; mi < 4; ++mi) {
    f32x4 z = {0.f, 0.f, 0.f, 0.f};
    lacc[mi] = z;
#pragma unroll
    for (int nb = 0; nb < 4; ++nb) oacc[mi][nb] = z;
  }

  bf16x8 onesf;
#pragma unroll
  for (int i = 0; i < 8; ++i) onesf[i] = (short)0x3F80;   // bf16 1.0

  // staging (per 2-wave grp pair = 128 lanes; tig = tid & 127)
  const int tig = tid & 127;
  const int slotK = tig & 7,  rowK = tig >> 3;     // K: 16 rows x 8 slots (+j*16)
  const int slotV = tig & 3,  rowV = tig >> 2;     // V: 32 rows x 4 slots (+j*32)
  const short* kp = Kb + base + (grp * 1024 + rowK) * HD_ + ((slotK ^ (rowK & 7)) * 8);
  const short* vp = Vtb + base + rowV * S_ + grp * 1024 + ((slotV ^ ((rowV >> 2) & 3)) * 8);
  lds_short* ldk = (lds_short*)(lK + grp * 2048 + tig * 8);
  lds_short* ldv = (lds_short*)(lV + grp * 2048 + tig * 8);

  auto stage = [&](int kt, int buf) {
#pragma unroll
    for (int j = 0; j < 2; ++j) {
      __builtin_amdgcn_global_load_lds((gbl_short*)(kp + kt * 32 * HD_ + j * 16 * HD_),
                                       ldk + buf * 4096 + j * 1024, 16, 0, 0);
      __builtin_amdgcn_global_load_lds((gbl_short*)(vp + kt * 32 + j * 32 * S_),
                                       ldv + buf * 4096 + j * 1024, 16, 0, 0);
    }
  };

  const int swzK = l15 & 7;                        // K 16B-group XOR key
  const int fsw  = (l15 >> 2) & 3;                 // V 16B-group XOR key
  const int g1 = (quad >> 1) ^ fsw;                // V physical group, keys quad*4+0..3
  const int g2 = (2 | (quad >> 1)) ^ fsw;          // V physical group, keys 16+quad*4+0..3
  const int vsub = (quad & 1) * 4;                 // 8B half within 16B group

  stage(0, 0);
  __syncthreads();

  for (int kt = 0; kt < 32; ++kt) {
    const int buf = kt & 1;
    if (kt < 31) stage(kt + 1, buf ^ 1);

    const short* lKc = lK + buf * 4096 + grp * 2048;
    const short* lVc = lV + buf * 4096 + grp * 2048;

    // S^T = K Q^T : sacc[mi][nb], rows=keys nb*16+quad*4+r, cols=q=l15
    f32x4 sacc[4][2];
#pragma unroll
    for (int mi = 0; mi < 4; ++mi)
#pragma unroll
      for (int nb = 0; nb < 2; ++nb) { f32x4 z = {0.f, 0.f, 0.f, 0.f}; sacc[mi][nb] = z; }
#pragma unroll
    for (int nb = 0; nb < 2; ++nb)
#pragma unroll
      for (int ks = 0; ks < 2; ++ks) {
        bf16x8 kf = *(const bf16x8*)(lKc + (nb * 16 + l15) * 64 + (((ks * 4 + quad) ^ swzK) * 8));
#pragma unroll
        for (int mi = 0; mi < 4; ++mi)
          sacc[mi][nb] = __builtin_amdgcn_mfma_f32_16x16x32_bf16(kf, qf[mi][ks], sacc[mi][nb], 0, 0, 0);
      }

    // P A-fragments built in registers: af[mi][j] = exp2(sacc[mi][j>>2][j&3])
    bf16x8 af[4];
#pragma unroll
    for (int mi = 0; mi < 4; ++mi)
#pragma unroll
      for (int j = 0; j < 8; ++j)
        af[mi][j] = bf16s(__builtin_amdgcn_exp2f(sacc[mi][j >> 2][j & 3]));

    // O += P V (same sigma on V's k): vf = two b64 runs per nbh
#pragma unroll
    for (int nbh = 0; nbh < 4; ++nbh) {
      const short* vrow = lVc + (nbh * 16 + l15) * 32 + vsub;
      bf16x4 v1 = *(const bf16x4*)(vrow + g1 * 8);
      bf16x4 v2 = *(const bf16x4*)(vrow + g2 * 8);
      bf16x8 vf = __builtin_shufflevector(v1, v2, 0, 1, 2, 3, 4, 5, 6, 7);
#pragma unroll
      for (int mi = 0; mi < 4; ++mi)
        oacc[mi][nbh] = __builtin_amdgcn_mfma_f32_16x16x32_bf16(af[mi], vf, oacc[mi][nbh], 0, 0, 0);
    }
#pragma unroll
    for (int mi = 0; mi < 4; ++mi)
      lacc[mi] = __builtin_amdgcn_mfma_f32_16x16x32_bf16(af[mi], onesf, lacc[mi], 0, 0, 0);
    __syncthreads();
  }

  // merge the two key-halves through LDS, normalize + write
  float* exch = (float*)smem;                      // 2 wq x 64q x 64hd f32 = 32 KB
  float* lex  = (float*)(smem + 32768);            // 128 floats
  if (grp == 1) {
#pragma unroll
    for (int mi = 0; mi < 4; ++mi)
#pragma unroll
      for (int nbh = 0; nbh < 4; ++nbh)
#pragma unroll
        for (int r = 0; r < 4; ++r)
          exch[wq * 4096 + (mi * 16 + quad * 4 + r) * 64 + nbh * 16 + l15] = oacc[mi][nbh][r];
    if (l15 == 0) {
#pragma unroll
      for (int mi = 0; mi < 4; ++mi)
#pragma unroll
        for (int r = 0; r < 4; ++r)
          lex[wq * 64 + mi * 16 + quad * 4 + r] = lacc[mi][r];
    }
  }
  __syncthreads();
  if (grp == 0) {
#pragma unroll
    for (int mi = 0; mi < 4; ++mi)
#pragma unroll
      for (int r = 0; r < 4; ++r) {
        int row = mi * 16 + quad * 4 + r;
        float l2 = lex[wq * 64 + row];
        float inv = 1.0f / (lacc[mi][r] + l2);
        int sg = q0 + row;
#pragma unroll
        for (int nbh = 0; nbh < 4; ++nbh) {
          float o2 = exch[wq * 4096 + row * 64 + nbh * 16 + l15];
          Ob[(b * S_ + sg) * D_ + h * HD_ + nbh * 16 + l15] =
              bf16s((oacc[mi][nbh][r] + o2) * inv);
        }
      }
  }
}

// ---------------- launcher ----------------
extern "C" void kernel_launch(void* const* d_in, const int* in_sizes, int n_in,
                              void* d_out, int out_size, void* d_ws, size_t ws_size,
                              hipStream_t stream) {
  (void)in_sizes; (void)n_in; (void)out_size; (void)ws_size;
  const float* x  = (const float*)d_in[0];
  const float* Wq = (const float*)d_in[1];
  const float* bq = (const float*)d_in[2];
  const float* Wk = (const float*)d_in[3];
  const float* bk = (const float*)d_in[4];
  const float* Wv = (const float*)d_in[5];
  const float* bv = (const float*)d_in[6];
  const float* Wo = (const float*)d_in[7];
  const float* bo = (const float*)d_in[8];
  float* out = (float*)d_out;

  char* ws = (char*)d_ws;
  short* xb  = (short*)(ws);
  short* Wqt = (short*)(ws + 8388608);
  short* Wkt = Wqt + 1048576;
  short* Wvt = Wkt + 1048576;
  short* Wot = Wvt + 1048576;
  short* Qb  = Wot + 1048576;
  short* Kb  = Qb + 4194304;
  short* Vtb = Kb + 4194304;
  short* Ob  = Vtb + 4194304;

  cast_x_kernel<<<4096, 256, 0, stream>>>(x, xb);
  transpose_cast_w<<<dim3(32, 32, 4), dim3(32, 8), 0, stream>>>(
      Wq, Wk, Wv, Wo, Wqt, Wkt, Wvt, Wot);
  qkv_gemm<<<dim3(32, 8, 3), 256, 0, stream>>>(
      xb, Wqt, Wkt, Wvt, bq, bk, bv, Qb, Kb, Vtb);
  attn_kernel<<<dim3(16, 16, 2), 256, 0, stream>>>(Qb, Kb, Vtb, Ob);
  out_gemm<<<dim3(32, 16), 256, 0, stream>>>(Ob, Wot, bo, out);
}